// Round 15
// baseline (1244.338 us; speedup 1.0000x reference)
//
#include <hip/hip_runtime.h>

typedef __attribute__((ext_vector_type(8))) __bf16 bf16x8;
typedef __attribute__((ext_vector_type(4))) float f32x4;
typedef __attribute__((ext_vector_type(16))) float f32x16;

__device__ __forceinline__ unsigned short fbf(float f) {
  union { float f; unsigned u; } x; x.f = f;
  unsigned r = x.u + 0x7fffu + ((x.u >> 16) & 1u);
  return (unsigned short)(r >> 16);
}
__device__ __forceinline__ float bf2f(unsigned short h) {
  union { unsigned u; float f; } x; x.u = ((unsigned)h) << 16;
  return x.f;
}

// ---- workspace byte offsets ----
#define OFF_WPL 0u
#define OFF_WP0 131072u
#define OFF_WT1 196608u                    // [9][8][8][2][64][8] bf16 fuse_w1 (frag layout)
#define OFF_WT2 1376256u                   // [9][4][8][2][64][8] bf16 fuse_w2 (frag layout)
#define OFF_BNS 1966080u
#define OFF_BNB 1967104u
#define OFF_T1  4194304u                   // [8][128][128][256] bf16
#define OFF_X0  (OFF_T1 + 67108864u)       // [8][256][256][256] bf16
#define OFF_Y   (OFF_X0 + 268435456u)      // [8][256][256][256] bf16
#define OFF_YF  OFF_T1                     // [8][256][256][128] bf16 (reuses dead t1+x0)

// ---------------- prep: weights -> bf16 re-layout, BN fold ----------------
// conv weights -> MFMA-fragment layout: [tap][cb][cib][ks][lane(64)][e(8)]
//   ci = cib*32 + ks*16 + (lane>>5)*8 + e ;  co = cb*32 + (lane&31)
__global__ void prep_kernel(const float* __restrict__ pl, const float* __restrict__ p0,
                            const float* __restrict__ w1, const float* __restrict__ w2,
                            const float* __restrict__ gam, const float* __restrict__ bet,
                            const float* __restrict__ mean, const float* __restrict__ var,
                            unsigned short* __restrict__ wpl, unsigned short* __restrict__ wp0,
                            unsigned short* __restrict__ wt1, unsigned short* __restrict__ wt2,
                            float* __restrict__ bns, float* __restrict__ bnb) {
  int t = blockIdx.x * blockDim.x + threadIdx.x;
  int stride = gridDim.x * blockDim.x;
  for (int i = t; i < 65536; i += stride) wpl[i] = fbf(pl[i]);
  for (int i = t; i < 32768; i += stride) wp0[i] = fbf(p0[i]);
  for (int i = t; i < 589824; i += stride) {
    int e = i & 7, l = (i >> 3) & 63, ks = (i >> 9) & 1;
    int cib = (i >> 10) & 7, cb = (i >> 13) & 7, tap = i >> 16;
    int ci = cib * 32 + ks * 16 + (l >> 5) * 8 + e;
    int co = cb * 32 + (l & 31);
    wt1[i] = fbf(w1[(co * 256 + ci) * 9 + tap]);
  }
  for (int i = t; i < 294912; i += stride) {
    int e = i & 7, l = (i >> 3) & 63, ks = (i >> 9) & 1;
    int cib = (i >> 10) & 7, cb = (i >> 13) & 3, tap = i >> 15;
    int ci = cib * 32 + ks * 16 + (l >> 5) * 8 + e;
    int co = cb * 32 + (l & 31);
    wt2[i] = fbf(w2[(co * 256 + ci) * 9 + tap]);
  }
  for (int i = t; i < 256; i += stride) {
    float s = gam[i] * rsqrtf(var[i] + 1e-5f);
    bns[i] = s; bnb[i] = bet[i] - mean[i] * s;
  }
}

// ---------------- 1x1 conv as GEMM (NCHW f32 in -> NHWC bf16 out) ----------------
template <int K, int HW, int WD, int EPI>
__global__ __launch_bounds__(512) void gemm1x1_kernel(
    const float* __restrict__ srcA, const float* __restrict__ srcB,
    const unsigned short* __restrict__ wmat,
    unsigned short* __restrict__ outp,
    const unsigned short* __restrict__ t1) {
  __shared__ unsigned short in_lds[128 * 32];
  __shared__ unsigned short w_lds[128 * 32];
  const int tid = threadIdx.x;
  const int pix0 = blockIdx.x * 128;
  const int co0 = blockIdx.y * 128;
  const int n = pix0 / HW;
  const int rem = pix0 % HW;
  const int h = rem / WD;
  const int w0 = rem % WD;
  const float* src = (n < 4) ? (srcA + (size_t)n * K * HW) : (srcB + (size_t)(n - 4) * K * HW);
  const float* rowbase = src + (size_t)h * WD + w0;
  const int wv = tid >> 6, lane = tid & 63;
  const int pw = wv >> 1, cw = wv & 1;
  const int l15 = lane & 15, k8 = lane >> 4;
  f32x4 zero = {0.f, 0.f, 0.f, 0.f};
  f32x4 acc[2][4];
#pragma unroll
  for (int i = 0; i < 2; i++)
#pragma unroll
    for (int j = 0; j < 4; j++) acc[i][j] = zero;
  const int sci = tid >> 4;
  const int sps = (tid & 15) * 8;
  const int wrow = tid >> 2, wsg = tid & 3;
  for (int cib = 0; cib < K / 32; ++cib) {
    int ci0 = cib * 32;
    __syncthreads();
    {
      const float* p = rowbase + (size_t)(ci0 + sci) * HW + sps;
      float4 v0 = *(const float4*)p;
      float4 v1 = *(const float4*)(p + 4);
      float vv[8] = {v0.x, v0.y, v0.z, v0.w, v1.x, v1.y, v1.z, v1.w};
#pragma unroll
      for (int i = 0; i < 8; i++) {
        int row = sps + i;
        int g = (sci >> 3) ^ ((row >> 1) & 3);
        in_lds[row * 32 + g * 8 + (sci & 7)] = fbf(vv[i]);
      }
    }
    {
      int4 v = *(const int4*)&wmat[(size_t)(co0 + wrow) * K + ci0 + wsg * 8];
      *(int4*)&w_lds[wrow * 32 + ((wsg ^ ((wrow >> 1) & 3)) << 3)] = v;
    }
    __syncthreads();
    bf16x8 b[4];
#pragma unroll
    for (int nf = 0; nf < 4; nf++) {
      int row = cw * 64 + nf * 16 + l15;
      b[nf] = *(const bf16x8*)&w_lds[row * 32 + ((k8 ^ ((row >> 1) & 3)) << 3)];
    }
#pragma unroll
    for (int mf = 0; mf < 2; mf++) {
      int row = pw * 32 + mf * 16 + l15;
      bf16x8 a = *(const bf16x8*)&in_lds[row * 32 + ((k8 ^ ((row >> 1) & 3)) << 3)];
#pragma unroll
      for (int nf = 0; nf < 4; nf++)
        acc[mf][nf] = __builtin_amdgcn_mfma_f32_16x16x32_bf16(a, b[nf], acc[mf][nf], 0, 0, 0);
    }
  }
  float fh = 0.f; int i0 = 0;
  if (EPI == 1) {
    float ph = (float)h * (127.0f / 255.0f);
    i0 = (int)ph; if (i0 > 126) i0 = 126;
    fh = ph - (float)i0;
  }
#pragma unroll
  for (int mf = 0; mf < 2; mf++) {
#pragma unroll
    for (int nf = 0; nf < 4; nf++) {
      int co = co0 + cw * 64 + nf * 16 + l15;
#pragma unroll
      for (int r = 0; r < 4; r++) {
        int m = pw * 32 + mf * 16 + k8 * 4 + r;
        float v = acc[mf][nf][r];
        if (EPI == 1) {
          int ww = w0 + m;
          float pww = (float)ww * (127.0f / 255.0f);
          int j0 = (int)pww; if (j0 > 126) j0 = 126;
          float fw = pww - (float)j0;
          const unsigned short* tb = t1 + ((size_t)(n * 128 + i0) * 128 + j0) * 256 + co;
          float a00 = bf2f(tb[0]);
          float a01 = bf2f(tb[256]);
          float a10 = bf2f(tb[128 * 256]);
          float a11 = bf2f(tb[128 * 256 + 256]);
          float top = a00 + fw * (a01 - a00);
          float bot = a10 + fw * (a11 - a10);
          v += top + fh * (bot - top);
        }
        outp[(size_t)(pix0 + m) * 256 + co] = fbf(v);
      }
    }
  }
}

// ---------------- 3x3 conv: R14 structure + 4-buffer ring (barrier every 2 cib) ----
// 256 thr = 4 waves, each one 32-co block; tile 4h x 32w x 128co.
// LDS ring: 4 bufs x 13056 B = 52224 B (2 blocks/CU proven at this footprint, R10).
// Iteration t: read buf[t&3]; stage t+2 into buf[(t+2)&3] (reg-staged, T14).
// Window pairs (2k,2k+1): read bufs {2k%4,(2k+1)%4}, write bufs {(2k+2)%4,(2k+3)%4}
// -- all distinct mod 4, so one lgkm-only barrier at the end of ODD t suffices.
template <int COT, int BNRELU>
__global__ __launch_bounds__(256, 2) void conv3x3_kernel(
    const unsigned short* __restrict__ inp,
    const unsigned short* __restrict__ wtr,
    unsigned short* __restrict__ outp,
    const float* __restrict__ bns, const float* __restrict__ bnb) {
  constexpr int WPT = COT / 32;
  __shared__ unsigned short xl[4][6528];
  const int tid = threadIdx.x;
  const int bx = blockIdx.x;
  const int n = bx >> 9;
  const int h0 = ((bx >> 3) & 63) * 4;
  const int w0 = (bx & 7) * 32;
  const int co0 = blockIdx.y * 128;
  const int lane = tid & 63, cw = tid >> 6;
  const int l31 = lane & 31, lh = lane >> 5;
  const int cb = (co0 >> 5) + cw;

  f32x16 acc[4];
#pragma unroll
  for (int m = 0; m < 4; m++)
#pragma unroll
    for (int r = 0; r < 16; r++) acc[m][r] = 0.f;

#define FRAG_ADDR(tap, ks, cc) ((((size_t)((tap) * WPT + cb) * 8 + (cc)) * 2 + (ks)) * 512 + lane * 8)

  bf16x8 B[3][3][2];
#pragma unroll
  for (int kh = 0; kh < 3; kh++)
#pragma unroll
    for (int kw = 0; kw < 3; kw++)
#pragma unroll
      for (int ks = 0; ks < 2; ks++)
        B[kh][kw][ks] = *(const bf16x8*)&wtr[FRAG_ADDR(kh * 3 + kw, ks, 0)];

  // prologue: stage cib 0 -> buf0, cib 1 -> buf1 (granule-major)
  const size_t nbase = (size_t)n * 256 * 256 * 256;
  for (int s = tid; s < 816; s += 256) {
    int p = s >> 2, g = s & 3;
    int row = p / 34, col = p - row * 34;
    int gh = h0 + row - 1, gw = w0 + col - 1;
    int4 v0 = make_int4(0, 0, 0, 0), v1 = make_int4(0, 0, 0, 0);
    if ((unsigned)gh < 256u && (unsigned)gw < 256u) {
      const unsigned short* base = &inp[nbase + ((size_t)gh * 256 + gw) * 256 + g * 8];
      v0 = *(const int4*)base;
      v1 = *(const int4*)(base + 32);
    }
    *(int4*)&xl[0][(g * 204 + p) * 8] = v0;
    *(int4*)&xl[1][(g * 204 + p) * 8] = v1;
  }
  __syncthreads();

  for (int cib = 0; cib < 8; ++cib) {
    const int cin = cib + 2;
    // (0) first-row A-frag reads issued FIRST: shortest path out of the barrier
    const unsigned short* xb = xl[cib & 3];
    bf16x8 af[2][6];
#pragma unroll
    for (int kw = 0; kw < 3; kw++)
#pragma unroll
      for (int ks = 0; ks < 2; ks++)
        af[0][kw * 2 + ks] = *(const bf16x8*)&xb[((ks * 2 + lh) * 204 + l31 + kw) * 8];
    // (1) issue staging loads for cib+2 early (reg-staged, T14 split)
    int4 vr[4]; bool va[4]; int ldst[4];
    if (cin < 8) {
#pragma unroll
      for (int q = 0; q < 4; ++q) {
        int s = tid + q * 256;
        va[q] = s < 816;
        int p = s >> 2, g = s & 3;
        int row = p / 34, col = p - row * 34;
        int gh = h0 + row - 1, gw = w0 + col - 1;
        ldst[q] = (g * 204 + p) * 8;
        vr[q] = make_int4(0, 0, 0, 0);
        if (va[q] && (unsigned)gh < 256u && (unsigned)gw < 256u)
          vr[q] = *(const int4*)&inp[nbase + ((size_t)gh * 256 + gw) * 256 + cin * 32 + g * 8];
      }
    }
    // (2) MFMA burst: batched A-reads, 1 row ahead; B reloads after last use
    __builtin_amdgcn_s_setprio(1);
#pragma unroll
    for (int r = 0; r < 6; ++r) {
      const int cur = r & 1, nxt = cur ^ 1;
      if (r < 5) {
#pragma unroll
        for (int kw = 0; kw < 3; kw++)
#pragma unroll
          for (int ks = 0; ks < 2; ks++)
            af[nxt][kw * 2 + ks] =
                *(const bf16x8*)&xb[((ks * 2 + lh) * 204 + (r + 1) * 34 + l31 + kw) * 8];
      }
#pragma unroll
      for (int kw = 0; kw < 3; kw++)
#pragma unroll
        for (int ks = 0; ks < 2; ks++)
#pragma unroll
          for (int kh = 0; kh < 3; kh++) {
            int m = r - kh;
            if (m >= 0 && m < 4)
              acc[m] = __builtin_amdgcn_mfma_f32_32x32x16_bf16(af[cur][kw * 2 + ks],
                                                               B[kh][kw][ks], acc[m], 0, 0, 0);
          }
      if (r >= 3 && cib < 7) {  // B[r-3] fully consumed; reload for next cib (L2-hot)
        int kh = r - 3;
#pragma unroll
        for (int kw = 0; kw < 3; ++kw)
#pragma unroll
          for (int ks = 0; ks < 2; ++ks)
            B[kh][kw][ks] = *(const bf16x8*)&wtr[FRAG_ADDR(kh * 3 + kw, ks, cib + 1)];
      }
    }
    __builtin_amdgcn_s_setprio(0);
    // (3) write staged tile into ring slot (cib+2)&3; lgkm-only barrier at odd cib.
    if (cin < 8) {
#pragma unroll
      for (int q = 0; q < 4; ++q)
        if (va[q]) *(int4*)&xl[cin & 3][ldst[q]] = vr[q];
    }
    if ((cib & 1) && cib < 7)
      asm volatile("s_waitcnt lgkmcnt(0)\ns_barrier" ::: "memory");
  }
#undef FRAG_ADDR

  // epilogue: D col=lane&31 -> co, row=(r&3)+8*(r>>2)+4*lh -> w offset
  const int coL = co0 + cw * 32 + l31;
  float s = 1.f, t = 0.f;
  if (BNRELU) { s = bns[coL]; t = bnb[coL]; }
#pragma unroll
  for (int m = 0; m < 4; ++m) {
    int h = h0 + m;
    size_t rowb = (((size_t)(n * 256 + h) * 256) + w0) * COT + coL;
#pragma unroll
    for (int r = 0; r < 16; ++r) {
      int wofs = (r & 3) + 8 * (r >> 2) + 4 * lh;
      float v = acc[m][r];
      if (BNRELU) { v = v * s + t; v = (v >= 0.f) ? v : 0.01f * v; }
      outp[rowb + (size_t)wofs * COT] = fbf(v);
    }
  }
}

// ---------------- crop gather: yf NHWC bf16 -> NC(ws)(ws) f32 ----------------
// LDS tile stride 140 shorts (70 words ≡ 6 mod 32): untranspose reads ~4-way;
// paired-channel u32 reads halve read instructions.
template <int WS, int PAD>
__global__ __launch_bounds__(256) void gather_kernel(
    const unsigned short* __restrict__ yf,
    const int* __restrict__ bidx, const int* __restrict__ widx,
    int bofs, float* __restrict__ outp) {
  const int WS2 = WS * WS;
  __shared__ unsigned short tile[WS * WS * 140];
  const int crop = blockIdx.x, tid = threadIdx.x;
  const int b = bidx[crop] + bofs;
  const int idx = widx[crop];
  const int r0 = (idx >> 5) * 8, c0 = (idx & 31) * 8;
  for (int t = tid; t < WS2 * 16; t += 256) {
    int p = t >> 4, sg = t & 15;
    int r = p / WS, cc = p - r * WS;
    int sr = r0 + r - PAD, sc = c0 + cc - PAD;
    int4 v = make_int4(0, 0, 0, 0);
    if ((unsigned)sr < 256u && (unsigned)sc < 256u)
      v = *(const int4*)&yf[(((size_t)(b * 256 + sr) * 256) + sc) * 128 + sg * 8];
    *(int2*)&tile[p * 140 + sg * 8] = make_int2(v.x, v.y);
    *(int2*)&tile[p * 140 + sg * 8 + 4] = make_int2(v.z, v.w);
  }
  __syncthreads();
  float* dst = outp + (size_t)crop * 128 * WS2;
  for (int o = tid; o < 64 * WS2; o += 256) {
    int cp = o / WS2, p = o - cp * WS2;
    unsigned v = *(const unsigned*)&tile[p * 140 + cp * 2];
    dst[(2 * cp) * WS2 + p] = bf2f((unsigned short)(v & 0xffffu));
    dst[(2 * cp + 1) * WS2 + p] = bf2f((unsigned short)(v >> 16));
  }
}

extern "C" void kernel_launch(void* const* d_in, const int* in_sizes, int n_in,
                              void* d_out, int out_size, void* d_ws, size_t ws_size,
                              hipStream_t stream) {
  const float* x0f = (const float*)d_in[0];
  const float* x0c = (const float*)d_in[1];
  const float* x1f = (const float*)d_in[2];
  const float* x1c = (const float*)d_in[3];
  const float* p0w = (const float*)d_in[4];
  const float* plw = (const float*)d_in[5];
  const float* fw1 = (const float*)d_in[6];
  const float* gam = (const float*)d_in[7];
  const float* bet = (const float*)d_in[8];
  const float* men = (const float*)d_in[9];
  const float* var = (const float*)d_in[10];
  const float* fw2 = (const float*)d_in[11];
  const int* b_idx = (const int*)d_in[12];
  const int* i_idx = (const int*)d_in[13];
  const int* j_idx = (const int*)d_in[14];
  (void)in_sizes; (void)n_in; (void)out_size; (void)ws_size;

  char* ws = (char*)d_ws;
  unsigned short* wpl = (unsigned short*)(ws + OFF_WPL);
  unsigned short* wp0 = (unsigned short*)(ws + OFF_WP0);
  unsigned short* wt1 = (unsigned short*)(ws + OFF_WT1);
  unsigned short* wt2 = (unsigned short*)(ws + OFF_WT2);
  float* bns = (float*)(ws + OFF_BNS);
  float* bnb = (float*)(ws + OFF_BNB);
  unsigned short* t1 = (unsigned short*)(ws + OFF_T1);
  unsigned short* x0 = (unsigned short*)(ws + OFF_X0);
  unsigned short* y = (unsigned short*)(ws + OFF_Y);
  unsigned short* yf = (unsigned short*)(ws + OFF_YF);
  float* out0 = (float*)d_out;
  float* out1 = out0 + (size_t)2048 * 128 * 64;

  prep_kernel<<<512, 256, 0, stream>>>(plw, p0w, fw1, fw2, gam, bet, men, var,
                                       wpl, wp0, wt1, wt2, bns, bnb);
  gemm1x1_kernel<256, 16384, 128, 0><<<dim3(1024, 2), 512, 0, stream>>>(x0c, x1c, wpl, t1, nullptr);
  gemm1x1_kernel<128, 65536, 256, 1><<<dim3(4096, 2), 512, 0, stream>>>(x0f, x1f, wp0, x0, t1);
  conv3x3_kernel<256, 1><<<dim3(4096, 2), 256, 0, stream>>>(x0, wt1, y, bns, bnb);
  conv3x3_kernel<128, 0><<<dim3(4096, 1), 256, 0, stream>>>(y, wt2, yf, nullptr, nullptr);
  gather_kernel<8, 0><<<2048, 256, 0, stream>>>(yf, b_idx, i_idx, 0, out0);
  gather_kernel<10, 1><<<2048, 256, 0, stream>>>(yf, b_idx, j_idx, 4, out1);
}

// Round 16
// 1174.956 us; speedup vs baseline: 1.0591x; 1.0591x over previous
//
#include <hip/hip_runtime.h>

typedef __attribute__((ext_vector_type(8))) __bf16 bf16x8;
typedef __attribute__((ext_vector_type(4))) float f32x4;
typedef __attribute__((ext_vector_type(16))) float f32x16;

__device__ __forceinline__ unsigned short fbf(float f) {
  union { float f; unsigned u; } x; x.f = f;
  unsigned r = x.u + 0x7fffu + ((x.u >> 16) & 1u);
  return (unsigned short)(r >> 16);
}
__device__ __forceinline__ float bf2f(unsigned short h) {
  union { unsigned u; float f; } x; x.u = ((unsigned)h) << 16;
  return x.f;
}

// ---- workspace byte offsets ----
#define OFF_WPL 0u
#define OFF_WP0 131072u
#define OFF_WT1 196608u                    // [9][8][8][2][64][8] bf16 fuse_w1 (frag layout)
#define OFF_WT2 1376256u                   // [9][4][8][2][64][8] bf16 fuse_w2 (frag layout)
#define OFF_BNS 1966080u
#define OFF_BNB 1967104u
#define OFF_T1  4194304u                   // [8][128][128][256] bf16
#define OFF_X0  (OFF_T1 + 67108864u)       // [8][256][256][256] bf16
#define OFF_Y   (OFF_X0 + 268435456u)      // [8][256][256][256] bf16
#define OFF_YF  OFF_T1                     // [8][256][256][128] bf16 (reuses dead t1+x0)

// ---------------- prep: weights -> bf16 re-layout, BN fold ----------------
// conv weights -> MFMA-fragment layout: [tap][cb][cib][ks][lane(64)][e(8)]
//   ci = cib*32 + ks*16 + (lane>>5)*8 + e ;  co = cb*32 + (lane&31)
__global__ void prep_kernel(const float* __restrict__ pl, const float* __restrict__ p0,
                            const float* __restrict__ w1, const float* __restrict__ w2,
                            const float* __restrict__ gam, const float* __restrict__ bet,
                            const float* __restrict__ mean, const float* __restrict__ var,
                            unsigned short* __restrict__ wpl, unsigned short* __restrict__ wp0,
                            unsigned short* __restrict__ wt1, unsigned short* __restrict__ wt2,
                            float* __restrict__ bns, float* __restrict__ bnb) {
  int t = blockIdx.x * blockDim.x + threadIdx.x;
  int stride = gridDim.x * blockDim.x;
  for (int i = t; i < 65536; i += stride) wpl[i] = fbf(pl[i]);
  for (int i = t; i < 32768; i += stride) wp0[i] = fbf(p0[i]);
  for (int i = t; i < 589824; i += stride) {
    int e = i & 7, l = (i >> 3) & 63, ks = (i >> 9) & 1;
    int cib = (i >> 10) & 7, cb = (i >> 13) & 7, tap = i >> 16;
    int ci = cib * 32 + ks * 16 + (l >> 5) * 8 + e;
    int co = cb * 32 + (l & 31);
    wt1[i] = fbf(w1[(co * 256 + ci) * 9 + tap]);
  }
  for (int i = t; i < 294912; i += stride) {
    int e = i & 7, l = (i >> 3) & 63, ks = (i >> 9) & 1;
    int cib = (i >> 10) & 7, cb = (i >> 13) & 3, tap = i >> 15;
    int ci = cib * 32 + ks * 16 + (l >> 5) * 8 + e;
    int co = cb * 32 + (l & 31);
    wt2[i] = fbf(w2[(co * 256 + ci) * 9 + tap]);
  }
  for (int i = t; i < 256; i += stride) {
    float s = gam[i] * rsqrtf(var[i] + 1e-5f);
    bns[i] = s; bnb[i] = bet[i] - mean[i] * s;
  }
}

// ---------------- 1x1 conv as GEMM (NCHW f32 in -> NHWC bf16 out) ----------------
// lgkm-only barriers: all LDS deps are lgkm ops; reg-staged global loads are
// ordered by the compiler's per-use vmcnt ladder, so next-cib loads stay in flight.
template <int K, int HW, int WD, int EPI>
__global__ __launch_bounds__(512) void gemm1x1_kernel(
    const float* __restrict__ srcA, const float* __restrict__ srcB,
    const unsigned short* __restrict__ wmat,
    unsigned short* __restrict__ outp,
    const unsigned short* __restrict__ t1) {
  __shared__ unsigned short in_lds[128 * 32];
  __shared__ unsigned short w_lds[128 * 32];
  const int tid = threadIdx.x;
  const int pix0 = blockIdx.x * 128;
  const int co0 = blockIdx.y * 128;
  const int n = pix0 / HW;
  const int rem = pix0 % HW;
  const int h = rem / WD;
  const int w0 = rem % WD;
  const float* src = (n < 4) ? (srcA + (size_t)n * K * HW) : (srcB + (size_t)(n - 4) * K * HW);
  const float* rowbase = src + (size_t)h * WD + w0;
  const int wv = tid >> 6, lane = tid & 63;
  const int pw = wv >> 1, cw = wv & 1;
  const int l15 = lane & 15, k8 = lane >> 4;
  f32x4 zero = {0.f, 0.f, 0.f, 0.f};
  f32x4 acc[2][4];
#pragma unroll
  for (int i = 0; i < 2; i++)
#pragma unroll
    for (int j = 0; j < 4; j++) acc[i][j] = zero;
  const int sci = tid >> 4;
  const int sps = (tid & 15) * 8;
  const int wrow = tid >> 2, wsg = tid & 3;
  for (int cib = 0; cib < K / 32; ++cib) {
    int ci0 = cib * 32;
    asm volatile("s_waitcnt lgkmcnt(0)\ns_barrier" ::: "memory");
    {
      const float* p = rowbase + (size_t)(ci0 + sci) * HW + sps;
      float4 v0 = *(const float4*)p;
      float4 v1 = *(const float4*)(p + 4);
      float vv[8] = {v0.x, v0.y, v0.z, v0.w, v1.x, v1.y, v1.z, v1.w};
#pragma unroll
      for (int i = 0; i < 8; i++) {
        int row = sps + i;
        int g = (sci >> 3) ^ ((row >> 1) & 3);
        in_lds[row * 32 + g * 8 + (sci & 7)] = fbf(vv[i]);
      }
    }
    {
      int4 v = *(const int4*)&wmat[(size_t)(co0 + wrow) * K + ci0 + wsg * 8];
      *(int4*)&w_lds[wrow * 32 + ((wsg ^ ((wrow >> 1) & 3)) << 3)] = v;
    }
    asm volatile("s_waitcnt lgkmcnt(0)\ns_barrier" ::: "memory");
    bf16x8 b[4];
#pragma unroll
    for (int nf = 0; nf < 4; nf++) {
      int row = cw * 64 + nf * 16 + l15;
      b[nf] = *(const bf16x8*)&w_lds[row * 32 + ((k8 ^ ((row >> 1) & 3)) << 3)];
    }
#pragma unroll
    for (int mf = 0; mf < 2; mf++) {
      int row = pw * 32 + mf * 16 + l15;
      bf16x8 a = *(const bf16x8*)&in_lds[row * 32 + ((k8 ^ ((row >> 1) & 3)) << 3)];
#pragma unroll
      for (int nf = 0; nf < 4; nf++)
        acc[mf][nf] = __builtin_amdgcn_mfma_f32_16x16x32_bf16(a, b[nf], acc[mf][nf], 0, 0, 0);
    }
  }
  float fh = 0.f; int i0 = 0;
  if (EPI == 1) {
    float ph = (float)h * (127.0f / 255.0f);
    i0 = (int)ph; if (i0 > 126) i0 = 126;
    fh = ph - (float)i0;
  }
#pragma unroll
  for (int mf = 0; mf < 2; mf++) {
#pragma unroll
    for (int nf = 0; nf < 4; nf++) {
      int co = co0 + cw * 64 + nf * 16 + l15;
#pragma unroll
      for (int r = 0; r < 4; r++) {
        int m = pw * 32 + mf * 16 + k8 * 4 + r;
        float v = acc[mf][nf][r];
        if (EPI == 1) {
          int ww = w0 + m;
          float pww = (float)ww * (127.0f / 255.0f);
          int j0 = (int)pww; if (j0 > 126) j0 = 126;
          float fw = pww - (float)j0;
          const unsigned short* tb = t1 + ((size_t)(n * 128 + i0) * 128 + j0) * 256 + co;
          float a00 = bf2f(tb[0]);
          float a01 = bf2f(tb[256]);
          float a10 = bf2f(tb[128 * 256]);
          float a11 = bf2f(tb[128 * 256 + 256]);
          float top = a00 + fw * (a01 - a00);
          float bot = a10 + fw * (a11 - a10);
          v += top + fh * (bot - top);
        }
        outp[(size_t)(pix0 + m) * 256 + co] = fbf(v);
      }
    }
  }
}

// ---------------- 3x3 conv (R14-exact, best measured): implicit GEMM, 32x32x16,
// weights in regs, granule-major LDS [buf][g(4)][pixel(204)][16B], reg-staged T14,
// lgkm-only per-cib barrier (B-reloads stay in flight across it). ----
template <int COT, int BNRELU>
__global__ __launch_bounds__(256, 2) void conv3x3_kernel(
    const unsigned short* __restrict__ inp,
    const unsigned short* __restrict__ wtr,
    unsigned short* __restrict__ outp,
    const float* __restrict__ bns, const float* __restrict__ bnb) {
  constexpr int WPT = COT / 32;
  __shared__ unsigned short xl[2][4 * 204 * 8];
  const int tid = threadIdx.x;
  const int bx = blockIdx.x;
  const int n = bx >> 9;
  const int h0 = ((bx >> 3) & 63) * 4;
  const int w0 = (bx & 7) * 32;
  const int co0 = blockIdx.y * 128;
  const int lane = tid & 63, cw = tid >> 6;
  const int l31 = lane & 31, lh = lane >> 5;
  const int cb = (co0 >> 5) + cw;

  f32x16 acc[4];
#pragma unroll
  for (int m = 0; m < 4; m++)
#pragma unroll
    for (int r = 0; r < 16; r++) acc[m][r] = 0.f;

#define FRAG_ADDR(tap, ks, cc) ((((size_t)((tap) * WPT + cb) * 8 + (cc)) * 2 + (ks)) * 512 + lane * 8)

  bf16x8 B[3][3][2];
#pragma unroll
  for (int kh = 0; kh < 3; kh++)
#pragma unroll
    for (int kw = 0; kw < 3; kw++)
#pragma unroll
      for (int ks = 0; ks < 2; ks++)
        B[kh][kw][ks] = *(const bf16x8*)&wtr[FRAG_ADDR(kh * 3 + kw, ks, 0)];

  // prologue: stage cib 0 into buf 0 (granule-major)
  const size_t nbase = (size_t)n * 256 * 256 * 256;
  for (int s = tid; s < 816; s += 256) {
    int p = s >> 2, g = s & 3;
    int row = p / 34, col = p - row * 34;
    int gh = h0 + row - 1, gw = w0 + col - 1;
    int4 v = make_int4(0, 0, 0, 0);
    if ((unsigned)gh < 256u && (unsigned)gw < 256u)
      v = *(const int4*)&inp[nbase + ((size_t)gh * 256 + gw) * 256 + g * 8];
    *(int4*)&xl[0][(g * 204 + p) * 8] = v;
  }
  __syncthreads();

  for (int cib = 0; cib < 8; ++cib) {
    const int cin = (cib + 1) & 7;
    // (0) first-row A-frag reads issued FIRST: shortest path out of the barrier
    const unsigned short* xb = xl[cib & 1];
    bf16x8 af[2][6];
#pragma unroll
    for (int kw = 0; kw < 3; kw++)
#pragma unroll
      for (int ks = 0; ks < 2; ks++)
        af[0][kw * 2 + ks] = *(const bf16x8*)&xb[((ks * 2 + lh) * 204 + l31 + kw) * 8];
    // (1) issue next x-tile loads early (reg-staged, T14 split)
    int4 vr[4]; bool va[4]; int ldst[4];
    if (cib < 7) {
#pragma unroll
      for (int q = 0; q < 4; ++q) {
        int s = tid + q * 256;
        va[q] = s < 816;
        int p = s >> 2, g = s & 3;
        int row = p / 34, col = p - row * 34;
        int gh = h0 + row - 1, gw = w0 + col - 1;
        ldst[q] = (g * 204 + p) * 8;
        vr[q] = make_int4(0, 0, 0, 0);
        if (va[q] && (unsigned)gh < 256u && (unsigned)gw < 256u)
          vr[q] = *(const int4*)&inp[nbase + ((size_t)gh * 256 + gw) * 256 + cin * 32 + g * 8];
      }
    }
    // (2) MFMA burst: batched A-reads, 1 row ahead; B reloads after last use
    __builtin_amdgcn_s_setprio(1);
#pragma unroll
    for (int r = 0; r < 6; ++r) {
      const int cur = r & 1, nxt = cur ^ 1;
      if (r < 5) {
#pragma unroll
        for (int kw = 0; kw < 3; kw++)
#pragma unroll
          for (int ks = 0; ks < 2; ks++)
            af[nxt][kw * 2 + ks] =
                *(const bf16x8*)&xb[((ks * 2 + lh) * 204 + (r + 1) * 34 + l31 + kw) * 8];
      }
#pragma unroll
      for (int kw = 0; kw < 3; kw++)
#pragma unroll
        for (int ks = 0; ks < 2; ks++)
#pragma unroll
          for (int kh = 0; kh < 3; kh++) {
            int m = r - kh;
            if (m >= 0 && m < 4)
              acc[m] = __builtin_amdgcn_mfma_f32_32x32x16_bf16(af[cur][kw * 2 + ks],
                                                               B[kh][kw][ks], acc[m], 0, 0, 0);
          }
      if (r >= 3) {  // B[r-3] fully consumed; reload for next cib (L2-hot)
        int kh = r - 3;
#pragma unroll
        for (int kw = 0; kw < 3; ++kw)
#pragma unroll
          for (int ks = 0; ks < 2; ++ks)
            B[kh][kw][ks] = *(const bf16x8*)&wtr[FRAG_ADDR(kh * 3 + kw, ks, cin)];
      }
    }
    __builtin_amdgcn_s_setprio(0);
    // (3) write next tile to other buffer; lgkm-only barrier (B-reloads keep flying)
    if (cib < 7) {
#pragma unroll
      for (int q = 0; q < 4; ++q)
        if (va[q]) *(int4*)&xl[cin & 1][ldst[q]] = vr[q];
      asm volatile("s_waitcnt lgkmcnt(0)\ns_barrier" ::: "memory");
    }
  }
#undef FRAG_ADDR

  // epilogue: D col=lane&31 -> co, row=(r&3)+8*(r>>2)+4*lh -> w offset
  const int coL = co0 + cw * 32 + l31;
  float s = 1.f, t = 0.f;
  if (BNRELU) { s = bns[coL]; t = bnb[coL]; }
#pragma unroll
  for (int m = 0; m < 4; ++m) {
    int h = h0 + m;
    size_t rowb = (((size_t)(n * 256 + h) * 256) + w0) * COT + coL;
#pragma unroll
    for (int r = 0; r < 16; ++r) {
      int wofs = (r & 3) + 8 * (r >> 2) + 4 * lh;
      float v = acc[m][r];
      if (BNRELU) { v = v * s + t; v = (v >= 0.f) ? v : 0.01f * v; }
      outp[rowb + (size_t)wofs * COT] = fbf(v);
    }
  }
}

// ---------------- crop gather: yf NHWC bf16 -> NC(ws)(ws) f32 ----------------
// LDS tile stride 140 shorts (70 words ≡ 6 mod 32): untranspose reads ~4-way;
// paired-channel u32 reads halve read instructions.
template <int WS, int PAD>
__global__ __launch_bounds__(256) void gather_kernel(
    const unsigned short* __restrict__ yf,
    const int* __restrict__ bidx, const int* __restrict__ widx,
    int bofs, float* __restrict__ outp) {
  const int WS2 = WS * WS;
  __shared__ unsigned short tile[WS * WS * 140];
  const int crop = blockIdx.x, tid = threadIdx.x;
  const int b = bidx[crop] + bofs;
  const int idx = widx[crop];
  const int r0 = (idx >> 5) * 8, c0 = (idx & 31) * 8;
  for (int t = tid; t < WS2 * 16; t += 256) {
    int p = t >> 4, sg = t & 15;
    int r = p / WS, cc = p - r * WS;
    int sr = r0 + r - PAD, sc = c0 + cc - PAD;
    int4 v = make_int4(0, 0, 0, 0);
    if ((unsigned)sr < 256u && (unsigned)sc < 256u)
      v = *(const int4*)&yf[(((size_t)(b * 256 + sr) * 256) + sc) * 128 + sg * 8];
    *(int2*)&tile[p * 140 + sg * 8] = make_int2(v.x, v.y);
    *(int2*)&tile[p * 140 + sg * 8 + 4] = make_int2(v.z, v.w);
  }
  __syncthreads();
  float* dst = outp + (size_t)crop * 128 * WS2;
  for (int o = tid; o < 64 * WS2; o += 256) {
    int cp = o / WS2, p = o - cp * WS2;
    unsigned v = *(const unsigned*)&tile[p * 140 + cp * 2];
    dst[(2 * cp) * WS2 + p] = bf2f((unsigned short)(v & 0xffffu));
    dst[(2 * cp + 1) * WS2 + p] = bf2f((unsigned short)(v >> 16));
  }
}

extern "C" void kernel_launch(void* const* d_in, const int* in_sizes, int n_in,
                              void* d_out, int out_size, void* d_ws, size_t ws_size,
                              hipStream_t stream) {
  const float* x0f = (const float*)d_in[0];
  const float* x0c = (const float*)d_in[1];
  const float* x1f = (const float*)d_in[2];
  const float* x1c = (const float*)d_in[3];
  const float* p0w = (const float*)d_in[4];
  const float* plw = (const float*)d_in[5];
  const float* fw1 = (const float*)d_in[6];
  const float* gam = (const float*)d_in[7];
  const float* bet = (const float*)d_in[8];
  const float* men = (const float*)d_in[9];
  const float* var = (const float*)d_in[10];
  const float* fw2 = (const float*)d_in[11];
  const int* b_idx = (const int*)d_in[12];
  const int* i_idx = (const int*)d_in[13];
  const int* j_idx = (const int*)d_in[14];
  (void)in_sizes; (void)n_in; (void)out_size; (void)ws_size;

  char* ws = (char*)d_ws;
  unsigned short* wpl = (unsigned short*)(ws + OFF_WPL);
  unsigned short* wp0 = (unsigned short*)(ws + OFF_WP0);
  unsigned short* wt1 = (unsigned short*)(ws + OFF_WT1);
  unsigned short* wt2 = (unsigned short*)(ws + OFF_WT2);
  float* bns = (float*)(ws + OFF_BNS);
  float* bnb = (float*)(ws + OFF_BNB);
  unsigned short* t1 = (unsigned short*)(ws + OFF_T1);
  unsigned short* x0 = (unsigned short*)(ws + OFF_X0);
  unsigned short* y = (unsigned short*)(ws + OFF_Y);
  unsigned short* yf = (unsigned short*)(ws + OFF_YF);
  float* out0 = (float*)d_out;
  float* out1 = out0 + (size_t)2048 * 128 * 64;

  prep_kernel<<<512, 256, 0, stream>>>(plw, p0w, fw1, fw2, gam, bet, men, var,
                                       wpl, wp0, wt1, wt2, bns, bnb);
  gemm1x1_kernel<256, 16384, 128, 0><<<dim3(1024, 2), 512, 0, stream>>>(x0c, x1c, wpl, t1, nullptr);
  gemm1x1_kernel<128, 65536, 256, 1><<<dim3(4096, 2), 512, 0, stream>>>(x0f, x1f, wp0, x0, t1);
  conv3x3_kernel<256, 1><<<dim3(4096, 2), 256, 0, stream>>>(x0, wt1, y, bns, bnb);
  conv3x3_kernel<128, 0><<<dim3(4096, 1), 256, 0, stream>>>(y, wt2, yf, nullptr, nullptr);
  gather_kernel<8, 0><<<2048, 256, 0, stream>>>(yf, b_idx, i_idx, 0, out0);
  gather_kernel<10, 1><<<2048, 256, 0, stream>>>(yf, b_idx, j_idx, 4, out1);
}